// Round 12
// baseline (147.094 us; speedup 1.0000x reference)
//
#include <hip/hip_runtime.h>

// B=32, S=127, new_seq=128, D=768, H=12, HD=64
#define NB 32
#define NS 128
#define SD 127
#define ND 768
#define NH 12
#define HD 64

__device__ inline float wredSum(float v){
  #pragma unroll
  for (int off=32; off>0; off>>=1) v += __shfl_xor(v, off);
  return v;
}
__device__ inline float wredMax(float v){
  #pragma unroll
  for (int off=32; off>0; off>>=1) v = fmaxf(v, __shfl_xor(v, off));
  return v;
}

// N0: fold uk (blk<144) + bkdot (blk 0) + ei rows (144..4207) + ctx:=bv init
// and counter zero (4208..4255)
__global__ __launch_bounds__(256)
void fold_ei_init(const float* __restrict__ Wk, const float* __restrict__ bk,
                  const float* __restrict__ desc, const float* __restrict__ Wa,
                  const float* __restrict__ bv,
                  float* __restrict__ uk, float* __restrict__ bkdot,
                  float* __restrict__ ei, float* __restrict__ ctx,
                  int* __restrict__ cnt){
  int blk = blockIdx.x, t = threadIdx.x;
  int wave = t >> 6, lane = t & 63;
  if (blk < 144){
    __shared__ float red[4][64];
    int h = blk/12, cb = blk%12;
    int c0 = t & 63, dg = t >> 6;
    const float* base = Wk + (size_t)(h*HD + dg*16)*ND + cb*64 + c0;
    float acc = 0.f;
    #pragma unroll
    for (int i=0;i<16;++i) acc += base[(size_t)i*ND] * Wa[64 + dg*16 + i];
    red[dg][c0] = acc;
    __syncthreads();
    if (dg==0) uk[h*ND + cb*64 + c0] = red[0][c0]+red[1][c0]+red[2][c0]+red[3][c0];
    if (blk==0 && t < NH){
      float a = 0.f;
      for (int d=0; d<64; ++d) a += bk[t*HD+d]*Wa[64+d];
      bkdot[t] = a;
    }
  } else if (blk < 144 + NB*SD){
    int bs = blk - 144;                  // 0..4063
    int b = bs / SD, s = bs % SD;
    float wea = Wa[128 + lane];
    const float* row = desc + (size_t)bs * ND;
    #pragma unroll
    for (int hh=0; hh<3; ++hh){
      int h = wave + hh*4;
      float v = row[h*HD + lane] * wea;
      v = wredSum(v);
      if (lane==0) ei[(size_t)(b*NH + h)*NS + s] = v;
    }
  } else {
    int idx = (blk - (144 + NB*SD))*256 + t;   // 0..12287 float4s of ctx
    int rem = idx % 384;
    int r = rem >> 4, q = rem & 15;
    int h = r >> 1;
    const float* bb = bv + h*HD + q*4;
    float4 v = { bb[0], bb[1], bb[2], bb[3] };
    ((float4*)ctx)[idx] = v;
    if (blk == 144 + NB*SD && t < NB) cnt[t] = 0;
  }
}

// N1: lk rows. 1024 blocks x 4 rows; uk in 36 regs/lane; 12 indep wredSums.
__global__ __launch_bounds__(256)
void lk_kernel(const float* __restrict__ nv, const float* __restrict__ uk,
               const float* __restrict__ bkdot, float* __restrict__ lk){
  __shared__ __align__(16) float S[4*ND];
  int blk = blockIdx.x, t = threadIdx.x, wave = t>>6, lane = t&63;
  float ukr[3][12], bkd[3];
  #pragma unroll
  for (int hh=0; hh<3; ++hh){
    int h = wave*3 + hh;
    bkd[hh] = bkdot[h];
    #pragma unroll
    for (int k=0;k<12;++k) ukr[hh][k] = uk[h*ND + lane + 64*k];
  }
  int j0 = blk*4;
  const float4* src = (const float4*)(nv + (size_t)j0*ND);
  ((float4*)S)[t]     = src[t];
  ((float4*)S)[t+256] = src[t+256];
  ((float4*)S)[t+512] = src[t+512];
  __syncthreads();
  float acc[12];
  #pragma unroll
  for (int rr=0; rr<4; ++rr)
    #pragma unroll
    for (int hh=0; hh<3; ++hh){
      float a = 0.f;
      #pragma unroll
      for (int k=0;k<12;++k) a += S[rr*ND + lane + 64*k]*ukr[hh][k];
      acc[rr*3+hh] = a;
    }
  #pragma unroll
  for (int i=0;i<12;++i) acc[i] = wredSum(acc[i]);
  if (lane == 0){
    int b = j0 >> 7, jb = j0 & 127;
    #pragma unroll
    for (int rr=0; rr<4; ++rr)
      #pragma unroll
      for (int hh=0; hh<3; ++hh)
        lk[(size_t)(b*NH + wave*3 + hh)*NS + jb + rr] = acc[rr*3+hh] + bkd[hh];
  }
}

// N2: block=(b, cc of 96 c's). softmax(24) -> m chunk (jg-reduced in LDS) ->
// V-proj partial -> atomicAdd ctx -> attn rows [cc*16,cc*16+16) -> last block
// per b stages ctx (coherence-point atomic loads) and writes basis slice.
__global__ __launch_bounds__(256)
void fused(const float* __restrict__ nv, const float* __restrict__ lk,
           const float* __restrict__ ei, const float* __restrict__ Wv,
           float* __restrict__ ctx, int* __restrict__ cnt,
           float* __restrict__ out){
  int blk = blockIdx.x;               // b*8 + cc
  int b = blk >> 3, cc = blk & 7;
  int t = threadIdx.x, wave = t >> 6, lane = t & 63;
  __shared__ __align__(16) float S[13104];
  __shared__ int flag;
  float* slk  = S;                    // 1536
  float* sei  = S + 1536;             // 1536
  float* wf   = S + 3072;             // 24*128 = 3072
  float* mred = S + 6144;             // 1152 float4 = 4608
  float* m    = S + 10752;            // 24*97 = 2328 (pad 97 kills bank conflicts)
  float* ctxb = S + 6144;             // alias mred (basis stage)

  for (int i=t; i<NH*NS; i+=256) slk[i] = lk[(size_t)b*NH*NS + i];
  for (int i=t; i<NH*NS; i+=256) sei[i] = ei[(size_t)b*NH*NS + i];
  __syncthreads();
  #pragma unroll
  for (int rr=0; rr<6; ++rr){
    int r = wave*6 + rr;
    int h = r >> 1, which = r & 1;
    const float* eirow = (which==0) ? (sei + (h%6)*NS) : (sei + h*NS);
    float g = (which==0) ? 1.f : (h>=6 ? 1.f : 0.f);
    float x0 = (lane>=1) ? slk[h*NS+lane] + g*eirow[lane-1] : -3.0e38f;
    float x1 = slk[h*NS+lane+64] + g*eirow[lane+63];
    float mm = wredMax(fmaxf(x0,x1));
    float e0 = (lane>=1) ? __expf(x0-mm) : 0.f;  // col 0 masked -> exactly 0
    float e1 = __expf(x1-mm);
    float s  = wredSum(e0+e1);
    float inv = 1.f/s;
    wf[r*NS + lane]    = e0*inv;
    wf[r*NS + lane+64] = e1*inv;
  }

  // m-chunk partials: 192 threads = 24 f4-cols x 8 jg (16 j each)
  float4 acc[24];
  #pragma unroll
  for (int r=0;r<24;++r) acc[r] = make_float4(0.f,0.f,0.f,0.f);
  int col = t % 24, jg = t / 24;
  __syncthreads();
  if (t < 192){
    const float4* nvb = (const float4*)nv;
    #pragma unroll 2
    for (int jj=0; jj<16; ++jj){
      int j = jg*16 + jj;
      float4 x = nvb[(size_t)(b*NS + j)*192 + cc*24 + col];
      #pragma unroll
      for (int r=0;r<24;++r){
        float wr = wf[r*NS + j];
        acc[r].x += wr*x.x; acc[r].y += wr*x.y;
        acc[r].z += wr*x.z; acc[r].w += wr*x.w;
      }
    }
  }
  // reduce jg partials: 4 passes of 6 rows
  #pragma unroll
  for (int p=0; p<4; ++p){
    __syncthreads();
    if (t < 192){
      #pragma unroll
      for (int rr=0; rr<6; ++rr)
        ((float4*)mred)[(rr*24 + col)*8 + jg] = acc[p*6+rr];
    }
    __syncthreads();
    if (t < 144){
      int rr = t / 24, c2 = t % 24;
      float4 s = make_float4(0.f,0.f,0.f,0.f);
      #pragma unroll
      for (int g=0; g<8; ++g){
        float4 v = ((float4*)mred)[(rr*24 + c2)*8 + g];
        s.x += v.x; s.y += v.y; s.z += v.z; s.w += v.w;
      }
      int r = p*6 + rr;
      m[r*97 + c2*4+0] = s.x; m[r*97 + c2*4+1] = s.y;
      m[r*97 + c2*4+2] = s.z; m[r*97 + c2*4+3] = s.w;
    }
  }
  __syncthreads();

  // V-proj partial over this c-chunk: thread owns 3 (h,d) rows
  #pragma unroll
  for (int i=0; i<3; ++i){
    int hd = t*3 + i;
    int h = hd >> 6, d = hd & 63;
    const float4* wr = (const float4*)(Wv + (size_t)hd*ND + cc*96);
    const float* m0 = m + (2*h)*97;
    const float* m1 = m0 + 97;
    float p0=0.f, p1=0.f;
    #pragma unroll
    for (int c4=0; c4<24; ++c4){
      float4 wv4 = wr[c4];
      int c = c4*4;
      p0 += wv4.x*m0[c] + wv4.y*m0[c+1] + wv4.z*m0[c+2] + wv4.w*m0[c+3];
      p1 += wv4.x*m1[c] + wv4.y*m1[c+1] + wv4.z*m1[c+2] + wv4.w*m1[c+3];
    }
    atomicAdd(&ctx[(size_t)(b*24 + 2*h    )*HD + d], p0);
    atomicAdd(&ctx[(size_t)(b*24 + 2*h + 1)*HD + d], p1);
  }

  // attn rows [cc*16, cc*16+16) for all 12 heads: 6144 float4
  float* abase = out + (size_t)NB*NS*ND + (size_t)(b*NH)*NS*NS;
  for (int idx=t; idx<6144; idx+=256){
    int h = idx >> 9;
    int rem = idx & 511;
    int il = rem >> 5, q = rem & 31;
    int i = cc*16 + il;
    const float* srcw = (i==0) ? (wf + h*2*NS) : (wf + (h*2+1)*NS);
    float4 v = { srcw[q*4], srcw[q*4+1], srcw[q*4+2], srcw[q*4+3] };
    ((float4*)(abase + (size_t)h*NS*NS))[i*32 + q] = v;
  }

  // finalize: barrier drains all threads' atomics (vmcnt0), then arrival count
  __syncthreads();
  if (t == 0){
    int old = __hip_atomic_fetch_add(cnt + b, 1, __ATOMIC_ACQ_REL,
                                     __HIP_MEMORY_SCOPE_AGENT);
    flag = (old == 7);
  }
  __syncthreads();
  if (flag){
    #pragma unroll
    for (int k=0;k<6;++k){
      int idx = t + k*256;             // 1536 ctx floats
      ctxb[idx] = __hip_atomic_load(&ctx[(size_t)b*1536 + idx],
                                    __ATOMIC_RELAXED, __HIP_MEMORY_SCOPE_AGENT);
    }
    __syncthreads();
    float4* bo = (float4*)(out + (size_t)b*NS*ND);
    #pragma unroll
    for (int k=0;k<96;++k){
      int idx = t + k*256;             // 24576 float4 = b's basis slice
      int i = idx / 192, rem = idx % 192;
      int h = rem >> 4, q = rem & 15;
      const float* srcc = ctxb + (2*h + (i!=0))*HD + q*4;
      float4 v = { srcc[0], srcc[1], srcc[2], srcc[3] };
      bo[idx] = v;
    }
  }
}

extern "C" void kernel_launch(void* const* d_in, const int* in_sizes, int n_in,
                              void* d_out, int out_size, void* d_ws, size_t ws_size,
                              hipStream_t stream) {
  const float* desc = (const float*)d_in[0];
  const float* nv   = (const float*)d_in[1];
  // d_in[2]=Wq, d_in[3]=bq: unused (softmax shift-invariance)
  const float* Wk   = (const float*)d_in[4];
  const float* bk   = (const float*)d_in[5];
  const float* Wv   = (const float*)d_in[6];
  const float* bv   = (const float*)d_in[7];
  const float* Wa   = (const float*)d_in[8];
  // d_in[9]=ba: unused (constant shift)
  float* out = (float*)d_out;
  float* ws  = (float*)d_ws;

  int*   cnt    = (int*)d_ws;       // 32 ints
  float* uk     = ws + 32;          // 9216
  float* bkdot  = ws + 9248;        // 16
  float* eibuf  = ws + 9264;        // 49152
  float* lkbuf  = ws + 58416;       // 49152
  float* ctx    = ws + 107568;      // 49152

  fold_ei_init<<<4256, 256, 0, stream>>>(Wk, bk, desc, Wa, bv, uk, bkdot,
                                         eibuf, ctx, cnt);
  lk_kernel   <<<1024, 256, 0, stream>>>(nv, uk, bkdot, lkbuf);
  fused       <<<256,  256, 0, stream>>>(nv, lkbuf, eibuf, Wv, ctx, cnt, out);
}

// Round 13
// 136.999 us; speedup vs baseline: 1.0737x; 1.0737x over previous
//
#include <hip/hip_runtime.h>

// B=32, S=127, new_seq=128, D=768, H=12, HD=64
#define NB 32
#define NS 128
#define SD 127
#define ND 768
#define NH 12
#define HD 64

__device__ inline float wredSum(float v){
  #pragma unroll
  for (int off=32; off>0; off>>=1) v += __shfl_xor(v, off);
  return v;
}
__device__ inline float wredMax(float v){
  #pragma unroll
  for (int off=32; off>0; off>>=1) v = fmaxf(v, __shfl_xor(v, off));
  return v;
}

// N0: fold uk (blk<144) + bkdot (blk 0) + ei rows (blk>=144)
__global__ __launch_bounds__(256)
void fold_ei(const float* __restrict__ Wk, const float* __restrict__ bk,
             const float* __restrict__ desc, const float* __restrict__ Wa,
             float* __restrict__ uk, float* __restrict__ bkdot,
             float* __restrict__ ei){
  int blk = blockIdx.x, t = threadIdx.x;
  int wave = t >> 6, lane = t & 63;
  if (blk < 144){
    __shared__ float red[4][64];
    int h = blk/12, cb = blk%12;
    int c0 = t & 63, dg = t >> 6;
    const float* base = Wk + (size_t)(h*HD + dg*16)*ND + cb*64 + c0;
    float acc = 0.f;
    #pragma unroll
    for (int i=0;i<16;++i) acc += base[(size_t)i*ND] * Wa[64 + dg*16 + i];
    red[dg][c0] = acc;
    __syncthreads();
    if (dg==0) uk[h*ND + cb*64 + c0] = red[0][c0]+red[1][c0]+red[2][c0]+red[3][c0];
    if (blk==0 && t < NH){
      float a = 0.f;
      for (int d=0; d<64; ++d) a += bk[t*HD+d]*Wa[64+d];
      bkdot[t] = a;
    }
  } else {
    int bs = blk - 144;                  // 0..4063
    int b = bs / SD, s = bs % SD;
    float wea = Wa[128 + lane];
    const float* row = desc + (size_t)bs * ND;
    #pragma unroll
    for (int hh=0; hh<3; ++hh){
      int h = wave + hh*4;
      float v = row[h*HD + lane] * wea;
      v = wredSum(v);
      if (lane==0) ei[(size_t)(b*NH + h)*NS + s] = v;
    }
  }
}

// N1: lk rows. 1024 blocks x 4 rows; uk in 36 regs/lane; 12 indep wredSums.
__global__ __launch_bounds__(256)
void lk_kernel(const float* __restrict__ nv, const float* __restrict__ uk,
               const float* __restrict__ bkdot, float* __restrict__ lk){
  __shared__ __align__(16) float S[4*ND];
  int blk = blockIdx.x, t = threadIdx.x, wave = t>>6, lane = t&63;
  float ukr[3][12], bkd[3];
  #pragma unroll
  for (int hh=0; hh<3; ++hh){
    int h = wave*3 + hh;
    bkd[hh] = bkdot[h];
    #pragma unroll
    for (int k=0;k<12;++k) ukr[hh][k] = uk[h*ND + lane + 64*k];
  }
  int j0 = blk*4;                        // 4 rows, same b (128 | 4)
  const float4* src = (const float4*)(nv + (size_t)j0*ND);
  ((float4*)S)[t]     = src[t];
  ((float4*)S)[t+256] = src[t+256];
  ((float4*)S)[t+512] = src[t+512];
  __syncthreads();
  float acc[12];
  #pragma unroll
  for (int rr=0; rr<4; ++rr)
    #pragma unroll
    for (int hh=0; hh<3; ++hh){
      float a = 0.f;
      #pragma unroll
      for (int k=0;k<12;++k) a += S[rr*ND + lane + 64*k]*ukr[hh][k];
      acc[rr*3+hh] = a;
    }
  #pragma unroll
  for (int i=0;i<12;++i) acc[i] = wredSum(acc[i]);
  if (lane == 0){
    int b = j0 >> 7, jb = j0 & 127;
    #pragma unroll
    for (int rr=0; rr<4; ++rr)
      #pragma unroll
      for (int hh=0; hh<3; ++hh)
        lk[(size_t)(b*NH + wave*3 + hh)*NS + jb + rr] = acc[rr*3+hh] + bkd[hh];
  }
}

// N2: per (b,jg16): all-24 softmax -> m partials over 8 j's (waves 0-2) +
// attn-tile rows [jg*8,jg*8+8) for all 12 heads. 512 blocks = 2/CU.
__global__ __launch_bounds__(256)
void msoft_attn(const float* __restrict__ nv, const float* __restrict__ lk,
                const float* __restrict__ ei, float* __restrict__ m_part,
                float* __restrict__ out){
  int blk = blockIdx.x;               // b*16 + jg
  int b = blk >> 4, jg = blk & 15;
  int t = threadIdx.x, wave = t >> 6, lane = t & 63;
  __shared__ float slk[NH*NS];
  __shared__ float sei[NH*NS];
  __shared__ float wf[24][NS];
  for (int i=t; i<NH*NS; i+=256) slk[i] = lk[(size_t)b*NH*NS + i];
  for (int i=t; i<NH*NS; i+=256) sei[i] = ei[(size_t)b*NH*NS + i];
  __syncthreads();
  #pragma unroll
  for (int rr=0; rr<6; ++rr){
    int r = wave*6 + rr;
    int h = r >> 1, which = r & 1;
    const float* eirow = (which==0) ? (sei + (h%6)*NS) : (sei + h*NS);
    float g = (which==0) ? 1.f : (h>=6 ? 1.f : 0.f);
    float x0 = (lane>=1) ? slk[h*NS+lane] + g*eirow[lane-1] : -3.0e38f;
    float x1 = slk[h*NS+lane+64] + g*eirow[lane+63];
    float mm = wredMax(fmaxf(x0,x1));
    float e0 = (lane>=1) ? __expf(x0-mm) : 0.f;  // col 0 masked -> exactly 0
    float e1 = __expf(x1-mm);
    float s  = wredSum(e0+e1);
    float inv = 1.f/s;
    wf[r][lane]    = e0*inv;
    wf[r][lane+64] = e1*inv;
  }
  __syncthreads();
  if (t < 192){                        // waves 0-2: m partials over 8 j's
    const float4* nvb = (const float4*)(nv + ((size_t)b*NS + jg*8)*ND);
    float4 acc[24];
    #pragma unroll
    for (int r=0;r<24;++r) acc[r] = make_float4(0.f,0.f,0.f,0.f);
    #pragma unroll
    for (int jj=0; jj<8; ++jj){
      float4 x = nvb[jj*192 + t];
      int j = jg*8 + jj;
      #pragma unroll
      for (int r=0;r<24;++r){
        float wr = wf[r][j];           // LDS broadcast, conflict-free
        acc[r].x += wr*x.x; acc[r].y += wr*x.y;
        acc[r].z += wr*x.z; acc[r].w += wr*x.w;
      }
    }
    #pragma unroll
    for (int r=0;r<24;++r)
      ((float4*)(m_part + ((size_t)(b*24 + r)*16 + jg)*ND))[t] = acc[r];
  }
  // attn rows [jg*8, jg*8+8) for all 12 heads: 3072 float4
  float* abase = out + (size_t)NB*NS*ND + (size_t)(b*NH)*NS*NS;
  for (int idx=t; idx<3072; idx+=256){
    int h = idx >> 8;
    int rem = idx & 255;
    int il = rem >> 5, q = rem & 31;
    int i = jg*8 + il;
    const float* srcw = (i==0) ? wf[h*2] : wf[h*2+1];
    float4 v = { srcw[q*4], srcw[q*4+1], srcw[q*4+2], srcw[q*4+3] };
    ((float4*)(abase + (size_t)h*NS*NS))[i*32 + q] = v;
  }
}

// N3: per (b,h): sum 16 partials (float4) -> V-proj -> basis write
__global__ __launch_bounds__(256)
void proj_basis(const float* __restrict__ m_part, const float* __restrict__ Wv,
                const float* __restrict__ bv, float* __restrict__ out){
  int bh = blockIdx.x;                // 0..383
  int b = bh / NH, h = bh % NH;
  int t = threadIdx.x, wave = t >> 6, lane = t & 63;
  __shared__ __align__(16) float msum[2*ND];
  __shared__ float cvec[2*HD];
  for (int i=t; i<384; i+=256){       // 384 float4 = 2 rows x 192
    int rl = (i >= 192);
    int c4 = i - rl*192;
    const float4* mp = (const float4*)(m_part + ((size_t)(b*24 + h*2 + rl)*16)*ND) + c4;
    float4 s = make_float4(0.f,0.f,0.f,0.f);
    #pragma unroll
    for (int g=0; g<16; ++g){
      float4 v = mp[g*192];
      s.x += v.x; s.y += v.y; s.z += v.z; s.w += v.w;
    }
    ((float4*)msum)[i] = s;
  }
  __syncthreads();
  #pragma unroll
  for (int dd=0; dd<16; ++dd){
    int d = wave*16 + dd;
    const float* wvr = Wv + (size_t)(h*HD + d)*ND;
    float p0=0.f, p1=0.f;
    #pragma unroll
    for (int k=0; k<12; ++k){
      float wv = wvr[lane + 64*k];
      p0 += wv*msum[lane + 64*k];
      p1 += wv*msum[ND + lane + 64*k];
    }
    p0 = wredSum(p0); p1 = wredSum(p1);
    if (lane==0){
      float bb = bv[h*HD + d];
      cvec[d]    = p0 + bb;
      cvec[64+d] = p1 + bb;
    }
  }
  __syncthreads();
  float* bo = out + (size_t)b*NS*ND + h*HD;
  #pragma unroll
  for (int k=0;k<8;++k){
    int idx = t + k*256;              // 2048 float4
    int i = idx>>4, q = idx&15;
    const float* srcc = (i==0) ? cvec : cvec+64;
    float4 v = { srcc[q*4], srcc[q*4+1], srcc[q*4+2], srcc[q*4+3] };
    *(float4*)(bo + (size_t)i*ND + q*4) = v;
  }
}

extern "C" void kernel_launch(void* const* d_in, const int* in_sizes, int n_in,
                              void* d_out, int out_size, void* d_ws, size_t ws_size,
                              hipStream_t stream) {
  const float* desc = (const float*)d_in[0];
  const float* nv   = (const float*)d_in[1];
  // d_in[2]=Wq, d_in[3]=bq: unused (softmax shift-invariance)
  const float* Wk   = (const float*)d_in[4];
  const float* bk   = (const float*)d_in[5];
  const float* Wv   = (const float*)d_in[6];
  const float* bv   = (const float*)d_in[7];
  const float* Wa   = (const float*)d_in[8];
  // d_in[9]=ba: unused (constant shift)
  float* out = (float*)d_out;
  float* ws  = (float*)d_ws;

  float* uk     = ws;               // 9216
  float* bkdot  = ws + 9216;        // 16
  float* eibuf  = ws + 9232;        // 49152
  float* lkbuf  = ws + 58384;       // 49152
  float* m_part = ws + 107536;      // 32*24*16*768 = 9437184

  fold_ei   <<<4208, 256, 0, stream>>>(Wk, bk, desc, Wa, uk, bkdot, eibuf);
  lk_kernel <<<1024, 256, 0, stream>>>(nv, uk, bkdot, lkbuf);
  msoft_attn<<<512,  256, 0, stream>>>(nv, lkbuf, eibuf, m_part, out);
  proj_basis<<<384,  256, 0, stream>>>(m_part, Wv, bv, out);
}